// Round 2
// baseline (524.856 us; speedup 1.0000x reference)
//
#include <hip/hip_runtime.h>

// Problem constants (from reference): B=1024, N=128, D=256, H=4, C=64, H*C=256
#define BB 1024
#define NN 128
#define DD 256
#define HC 256
#define NP1 129

typedef _Float16 f16;
typedef _Float16 f16x8 __attribute__((ext_vector_type(8)));
typedef float f32x4 __attribute__((ext_vector_type(4)));

// Workspace layout (f16 elements):
//   [0      ) WkWeT [256][512]  : row f, k<256 -> Wk[k][f], k>=256 -> We[k-256][f]
//   [131072 ) WvWeT [256][512]
//   [262144 ) WsT   [256][256]  : Wskip transposed
//   [327680 ) WqT   [256][256]  : Wq transposed
// total 393216 f16 = 786432 bytes
#define WS_WKWE 0
#define WS_WVWE 131072
#define WS_WS   262144
#define WS_WQ   327680

__global__ __launch_bounds__(256) void pack_w(
    const float* __restrict__ Wq, const float* __restrict__ Wk,
    const float* __restrict__ Wv, const float* __restrict__ We,
    const float* __restrict__ Ws, f16* __restrict__ ws) {
  int idx = blockIdx.x * 256 + threadIdx.x;  // 0..131071
  int f = idx >> 9;
  int k = idx & 511;
  float kv, vv;
  if (k < 256) {
    kv = Wk[k * 256 + f];
    vv = Wv[k * 256 + f];
  } else {
    float ev = We[(k - 256) * 256 + f];
    kv = ev;
    vv = ev;
  }
  ws[WS_WKWE + f * 512 + k] = (f16)kv;
  ws[WS_WVWE + f * 512 + k] = (f16)vv;
  if (k < 256) {
    ws[WS_WS + f * 256 + k] = (f16)Ws[k * 256 + f];
    ws[WS_WQ + f * 256 + k] = (f16)Wq[k * 256 + f];
  }
}

// One block per batch element b. 512 threads = 8 waves, wave grid 2(M) x 4(N).
// Wave (wm,wn): rows 64*wm..+63 (neighbors), cols 64*wn..+63 (head h = wn).
// V-GEMM eliminated: agg = (alpha @ xe) @ WvWe + bv  (linearity of aggregation).
__global__ __launch_bounds__(512, 2) void fused_gtn(
    const float* __restrict__ central,  // [B,1,256]
    const float* __restrict__ neigh,    // [B,128,256]
    const float* __restrict__ edge,     // [B,128,256]
    const float* __restrict__ bq, const float* __restrict__ bk,
    const float* __restrict__ bv, const float* __restrict__ bskip,
    const f16* __restrict__ ws, float* __restrict__ out) {
  // xe tile [128 rows][512 k] f16, XOR-swizzled: elem = row*512 + (k ^ ((row&7)<<3))
  __shared__ __align__(16) f16 xe[128 * 512];   // 128 KiB
  __shared__ float c_lds[256];
  __shared__ float q_lds[256];       // q[h*64+c]
  __shared__ float sc[4 * 128];      // raw scores [h][n]
  __shared__ float alphaT[128 * 4];  // softmaxed, [n][h] for float4 broadcast reads
  __shared__ float z_lds[4 * 512];   // z[h][k] = sum_n alpha[h][n]*xe[n][k]
  __shared__ float aggbuf[256];      // [h*64+c]
  __shared__ float skipc[256];

  const int b = blockIdx.x;
  const int t = threadIdx.x;
  const f16* WkWeT = ws + WS_WKWE;
  const f16* WvWeT = ws + WS_WVWE;
  const f16* WsT = ws + WS_WS;
  const f16* WqT = ws + WS_WQ;

  // ---------------- stage x,e -> fp16 swizzled LDS; c -> f32 LDS ----------------
  {
    const float* xg = neigh + (size_t)b * (NN * DD);
    const float* eg = edge + (size_t)b * (NN * DD);
#pragma unroll
    for (int i = 0; i < 8; ++i) {
      int chunk = t + i * 512;        // 0..4095 ; 32 chunks of 8 elems per row
      int row = chunk >> 5;
      int k = (chunk & 31) << 3;
      float4 a0 = *(const float4*)(xg + row * 256 + k);
      float4 a1 = *(const float4*)(xg + row * 256 + k + 4);
      f16x8 h;
      h[0] = (f16)a0.x; h[1] = (f16)a0.y; h[2] = (f16)a0.z; h[3] = (f16)a0.w;
      h[4] = (f16)a1.x; h[5] = (f16)a1.y; h[6] = (f16)a1.z; h[7] = (f16)a1.w;
      *(f16x8*)&xe[row * 512 + (k ^ ((row & 7) << 3))] = h;
      a0 = *(const float4*)(eg + row * 256 + k);
      a1 = *(const float4*)(eg + row * 256 + k + 4);
      h[0] = (f16)a0.x; h[1] = (f16)a0.y; h[2] = (f16)a0.z; h[3] = (f16)a0.w;
      h[4] = (f16)a1.x; h[5] = (f16)a1.y; h[6] = (f16)a1.z; h[7] = (f16)a1.w;
      int ke = k + 256;
      *(f16x8*)&xe[row * 512 + (ke ^ ((row & 7) << 3))] = h;
    }
    if (t < 256) {
      c_lds[t] = central[b * 256 + t];
      aggbuf[t] = 0.f;
    }
  }
  __syncthreads();

  // ---------------- GEMVs on the central row: q (t<256) / skip_c (t>=256) -------
  {
    int hc = t & 255;
    const f16* wrow = (t < 256) ? (WqT + hc * 256) : (WsT + hc * 256);
    float accv[8] = {0.f, 0.f, 0.f, 0.f, 0.f, 0.f, 0.f, 0.f};
    for (int j = 0; j < 32; ++j) {
      f16x8 wv = *(const f16x8*)(wrow + j * 8);
      const float* cp = c_lds + j * 8;
#pragma unroll
      for (int u = 0; u < 8; ++u) accv[u] += cp[u] * (float)wv[u];
    }
    float acc = ((accv[0] + accv[1]) + (accv[2] + accv[3])) +
                ((accv[4] + accv[5]) + (accv[6] + accv[7]));
    if (t < 256) q_lds[hc] = acc + bq[hc];
    else skipc[hc] = acc + bskip[hc];
  }
  __syncthreads();

  const int w = t >> 6;
  const int l = t & 63;
  const int wm = w >> 2;   // 0..1  (row half)
  const int wn = w & 3;    // 0..3  (col block == head h)
  const int l15 = l & 15;
  const int l4 = l >> 4;

  // ---------------- K GEMM: [x|e] (128x512) @ WkWe (512x256), wave tile 64x64 ---
  f32x4 aK[4][4] = {};
  for (int ks = 0; ks < 16; ++ks) {
    int k0 = ks * 32 + l4 * 8;
    f16x8 a[4];
#pragma unroll
    for (int mf = 0; mf < 4; ++mf) {
      int row = 64 * wm + 16 * mf + l15;
      a[mf] = *(const f16x8*)&xe[row * 512 + (k0 ^ ((row & 7) << 3))];
    }
#pragma unroll
    for (int nf = 0; nf < 4; ++nf) {
      int col = 64 * wn + 16 * nf + l15;
      f16x8 bk8 = *(const f16x8*)(WkWeT + col * 512 + k0);
#pragma unroll
      for (int mf = 0; mf < 4; ++mf)
        aK[mf][nf] = __builtin_amdgcn_mfma_f32_16x16x32_f16(a[mf], bk8, aK[mf][nf], 0, 0, 0);
    }
  }

  // ---------------- scores: s[n] = sum_c q[h,c]*(K+bk)[n,c] / 8 -----------------
  {
    float qv[4], bkv[4];
#pragma unroll
    for (int nf = 0; nf < 4; ++nf) {
      int col = 64 * wn + 16 * nf + l15;
      qv[nf] = q_lds[col];
      bkv[nf] = bk[col];
    }
#pragma unroll
    for (int mf = 0; mf < 4; ++mf) {
#pragma unroll
      for (int i = 0; i < 4; ++i) {
        float s = 0.f;
#pragma unroll
        for (int nf = 0; nf < 4; ++nf) s += (aK[mf][nf][i] + bkv[nf]) * qv[nf];
        s += __shfl_xor(s, 1);
        s += __shfl_xor(s, 2);
        s += __shfl_xor(s, 4);
        s += __shfl_xor(s, 8);
        if (l15 == 0) sc[wn * 128 + 64 * wm + 16 * mf + 4 * l4 + i] = s * 0.125f;
      }
    }
  }
  __syncthreads();

  // ---------------- softmax over n (waves 0..3, h = w) -> alphaT[n][h] ----------
  if (w < 4) {
    float s0 = sc[w * 128 + l];
    float s1 = sc[w * 128 + 64 + l];
    float m = fmaxf(s0, s1);
#pragma unroll
    for (int off = 32; off >= 1; off >>= 1) m = fmaxf(m, __shfl_xor(m, off));
    float p0 = __expf(s0 - m);
    float p1 = __expf(s1 - m);
    float sum = p0 + p1;
#pragma unroll
    for (int off = 32; off >= 1; off >>= 1) sum += __shfl_xor(sum, off);
    float inv = 1.f / sum;
    alphaT[l * 4 + w] = p0 * inv;
    alphaT[(64 + l) * 4 + w] = p1 * inv;
  }
  __syncthreads();

  // ---------------- z[h][k] = sum_n alpha[h][n] * xe[n][k]  (thread t -> k=t) ---
  {
    float z0 = 0.f, z1 = 0.f, z2 = 0.f, z3 = 0.f;
    for (int n = 0; n < 128; ++n) {
      float4 al = *(const float4*)&alphaT[n * 4];   // same addr across lanes: broadcast
      float xv = (float)xe[n * 512 + (t ^ ((n & 7) << 3))];
      z0 += al.x * xv;
      z1 += al.y * xv;
      z2 += al.z * xv;
      z3 += al.w * xv;
    }
    z_lds[0 * 512 + t] = z0;
    z_lds[1 * 512 + t] = z1;
    z_lds[2 * 512 + t] = z2;
    z_lds[3 * 512 + t] = z3;
  }
  __syncthreads();

  // ---------------- agg[col] = sum_k z[h][k]*WvWeT[col][k]  (2 threads/col) -----
  {
    int col = t & 255;
    int h = col >> 6;
    int kbase = (t >> 8) * 256;
    const f16* wrow = WvWeT + col * 512 + kbase;
    const float* zrow = z_lds + h * 512 + kbase;
    float acc = 0.f;
#pragma unroll
    for (int j = 0; j < 32; ++j) {
      f16x8 wv = *(const f16x8*)(wrow + j * 8);
      const float* zp = zrow + j * 8;
#pragma unroll
      for (int u = 0; u < 8; ++u) acc += zp[u] * (float)wv[u];
    }
    atomicAdd(&aggbuf[col], acc);
  }

  // ---------------- skip GEMM for neighbor rows (x @ Wskip + bskip) -------------
  {
    f32x4 aS[4][4] = {};
    for (int ks = 0; ks < 8; ++ks) {
      int k0 = ks * 32 + l4 * 8;
      f16x8 a[4];
#pragma unroll
      for (int mf = 0; mf < 4; ++mf) {
        int row = 64 * wm + 16 * mf + l15;
        a[mf] = *(const f16x8*)&xe[row * 512 + (k0 ^ ((row & 7) << 3))];
      }
#pragma unroll
      for (int nf = 0; nf < 4; ++nf) {
        int col = 64 * wn + 16 * nf + l15;
        f16x8 bs8 = *(const f16x8*)(WsT + col * 256 + k0);
#pragma unroll
        for (int mf = 0; mf < 4; ++mf)
          aS[mf][nf] = __builtin_amdgcn_mfma_f32_16x16x32_f16(a[mf], bs8, aS[mf][nf], 0, 0, 0);
      }
    }
#pragma unroll
    for (int nf = 0; nf < 4; ++nf) {
      int col = 64 * wn + 16 * nf + l15;
      float bsk = bskip[col];
#pragma unroll
      for (int mf = 0; mf < 4; ++mf) {
#pragma unroll
        for (int i = 0; i < 4; ++i) {
          int row = 64 * wm + 16 * mf + 4 * l4 + i;
          out[((size_t)b * NP1 + 1 + row) * 256 + col] = aS[mf][nf][i] + bsk;
        }
      }
    }
  }
  __syncthreads();

  // ---------------- central row: skip_c + agg + bv (sum alpha = 1) --------------
  if (t < 256) {
    out[(size_t)b * NP1 * 256 + t] = skipc[t] + aggbuf[t] + bv[t];
  }
}

extern "C" void kernel_launch(void* const* d_in, const int* in_sizes, int n_in,
                              void* d_out, int out_size, void* d_ws, size_t ws_size,
                              hipStream_t stream) {
  (void)in_sizes; (void)n_in; (void)out_size; (void)ws_size;
  const float* central = (const float*)d_in[0];
  const float* neigh   = (const float*)d_in[1];
  const float* edge    = (const float*)d_in[2];
  const float* Wq      = (const float*)d_in[3];
  const float* bq      = (const float*)d_in[4];
  const float* Wk      = (const float*)d_in[5];
  const float* bk      = (const float*)d_in[6];
  const float* Wv      = (const float*)d_in[7];
  const float* bv      = (const float*)d_in[8];
  const float* We      = (const float*)d_in[9];
  const float* Ws      = (const float*)d_in[10];
  const float* bsk     = (const float*)d_in[11];
  f16* ws = (f16*)d_ws;        // needs 786432 bytes
  float* out = (float*)d_out;

  pack_w<<<512, 256, 0, stream>>>(Wq, Wk, Wv, We, Ws, ws);
  fused_gtn<<<BB, 512, 0, stream>>>(central, neigh, edge, bq, bk, bv, bsk, ws, out);
}